// Round 10
// baseline (3279.885 us; speedup 1.0000x reference)
//
#include <hip/hip_runtime.h>
#include <hip/hip_bf16.h>

typedef __attribute__((ext_vector_type(8))) short short8;
typedef __attribute__((ext_vector_type(4))) float floatx4;
typedef unsigned short u16;
typedef unsigned long long u64;

#define SCOPE_AGENT __HIP_MEMORY_SCOPE_AGENT

// B=128, T=256, D=6, H=512, 4H=2048, NC=4, PS=12

__device__ __forceinline__ u16 f2b(float f){
  union { float fl; unsigned u; } v; v.fl = f;
  unsigned r = v.u + 0x7fffu + ((v.u >> 16) & 1u);   // RNE bf16
  return (u16)(r >> 16);
}
__device__ __forceinline__ float b2f(u16 b){
  union { unsigned u; float f; } v; v.u = ((unsigned)b) << 16; return v.f;
}

// ---- agent-scope atomics (publish path; proven) ----
__device__ __forceinline__ u64 ldc64(const u64* p){
  return __hip_atomic_load(p, __ATOMIC_RELAXED, SCOPE_AGENT);
}
__device__ __forceinline__ void stc64(u64* p, u64 v){
  __hip_atomic_store(p, v, __ATOMIC_RELAXED, SCOPE_AGENT);
}

// poll deadline (~0.5 s @ 100 MHz wall clock)
__device__ __forceinline__ bool expired(long long t0){
  return (wall_clock64() - t0) > 50000000LL;
}

// ---------------- prep kernels (R0 verbatim) ----------------

__global__ void reorder_w_k(const float* __restrict__ W, u16* __restrict__ out){
  int idx = blockIdx.x*256 + threadIdx.x;       // 2048*512
  int r = idx >> 9, k = idx & 511;
  int rp = ((r & 511) << 2) | (r >> 9);
  out[rp*512 + k] = f2b(W[idx]);
}
__global__ void prep_wx0_k(const float* __restrict__ W, u16* __restrict__ out){
  int idx = blockIdx.x*256 + threadIdx.x;       // 2048*32
  int r = idx >> 5, k = idx & 31;
  int rp = ((r & 511) << 2) | (r >> 9);
  out[rp*32 + k] = (k < 6) ? f2b(W[r*6 + k]) : (u16)0;
}
__global__ void prep_bias_k(const float* __restrict__ bih, const float* __restrict__ bhh,
                            float* __restrict__ out){
  int r = blockIdx.x*256 + threadIdx.x;         // 2048
  int rp = ((r & 511) << 2) | (r >> 9);
  out[rp] = bih[r] + bhh[r];
}
__global__ void prep_x_k(const float* __restrict__ x, u16* __restrict__ out){
  int idx = blockIdx.x*256 + threadIdx.x;       // 256*128*32
  int t = idx >> 12; int rem = idx & 4095; int b = rem >> 5; int k = rem & 31;
  out[idx] = (k < 6) ? f2b(x[(b*256 + t)*6 + k]) : (u16)0;
}

// ---------------- persistent LSTM kernel ----------------

struct PK {
  const u16 *Xb, *Wx0, *W0hh, *W1ih, *W1hh, *Wd0ih, *Wd0hh, *Wd1ih, *Wd1hh;
  const float *Bs;              // 4x2048 gate-interleaved biases
  u16 *h0b, *h1b;               // bf16 DEPTH-4 h rings [4][128][512], slot = tau&3
  unsigned *F;                  // [0..63]=l0 (mh*32+nt), [64..127]=l1, [128..129]=heads
  const float *fcW, *fcb, *clsW, *clsb, *regW, *regb;
  float *out;
};

#define HB 65536   // u16 elements per ring slot (128 x 512)

// flag poll — wave 0 only; lanes 0..31 check l0 flags vs thr0, lanes 32..63
// check l1 flags vs thr1; lane 0 optionally checks heads flag (thrh>0).
__device__ __forceinline__ void pollF(const unsigned* F, int mh, int thr0, int thr1,
                                      int thrh, long long t0){
  const int lane = threadIdx.x & 63;
  const unsigned* ap = (lane < 32) ? (F + mh*32 + lane) : (F + 64 + mh*32 + (lane - 32));
  const int thr = (lane < 32) ? thr0 : thr1;
  for(;;){
    int v = (int)__hip_atomic_load(ap, __ATOMIC_RELAXED, SCOPE_AGENT);
    bool ok = (v >= thr);
    if (thrh > 0 && lane == 0)
      ok = ok && ((int)__hip_atomic_load(F + 128 + mh, __ATOMIC_RELAXED, SCOPE_AGENT) >= thrh);
    if (__all(ok)) return;
    if (expired(t0)) return;
    if (__any((thr - v) > 2)) __builtin_amdgcn_s_sleep(16);
    else                      __builtin_amdgcn_s_sleep(1);
  }
}

// One LSTM step tile for wg (role, mh, nt): 64 batches x 64 gates (R0-proven
// structure). h reads are PLAIN CACHED loads — caller has executed an
// agent-acquire fence after observing the producer flags, so stale L1/L2
// lines are invalidated and the first reader per XCD pulls MALL->L2; later
// co-located wgs hit the shared L2 (the 32x broadcast dedup).
template<int NK1>
__device__ __forceinline__ void lstm_step(
    const u16* __restrict__ A1, int a1rowlen, const u16* __restrict__ ldsW1, int st1,
    const u16* __restrict__ A2, const u16* __restrict__ ldsW2,
    const float* __restrict__ biasp, u16* __restrict__ hdst,
    float* creg, float (*g)[69],
    int mh, int nt, int wv, int lane)
{
  const int lrow = lane & 15, kq = lane >> 4;
  const int arow = mh*64 + wv*16 + lrow;
  short8 a1[NK1], a2[16];
  {
    const u16* p1 = A1 + arow*a1rowlen + kq*8;
    #pragma unroll
    for (int k = 0; k < NK1; ++k) a1[k] = *(const short8*)(p1 + k*32);
    const u16* p2 = A2 + arow*512 + kq*8;
    #pragma unroll
    for (int k = 0; k < 16; ++k) a2[k] = *(const short8*)(p2 + k*32);
  }
  floatx4 acc[4];
  #pragma unroll
  for (int nn = 0; nn < 4; ++nn) acc[nn] = (floatx4){0.f,0.f,0.f,0.f};
  #pragma unroll
  for (int nn = 0; nn < 4; ++nn){
    const u16* wb = ldsW1 + (nn*16 + lrow)*st1 + kq*8;
    #pragma unroll
    for (int k = 0; k < NK1; ++k)
      acc[nn] = __builtin_amdgcn_mfma_f32_16x16x32_bf16(a1[k], *(const short8*)(wb + k*32), acc[nn], 0,0,0);
  }
  #pragma unroll
  for (int nn = 0; nn < 4; ++nn){
    const u16* wb = ldsW2 + (nn*16 + lrow)*520 + kq*8;
    #pragma unroll
    for (int k = 0; k < 16; ++k)
      acc[nn] = __builtin_amdgcn_mfma_f32_16x16x32_bf16(a2[k], *(const short8*)(wb + k*32), acc[nn], 0,0,0);
  }
  // C/D layout: row(m) = kq*4 + r, col(n) = lane&15 -> g rows wv*16..+15 only
  #pragma unroll
  for (int nn = 0; nn < 4; ++nn){
    float bn = biasp[nn*16 + lrow];
    #pragma unroll
    for (int r = 0; r < 4; ++r)
      g[wv*16 + kq*4 + r][nn*16 + lrow] = acc[nn][r] + bn;
  }
  __builtin_amdgcn_wave_barrier();   // intra-wave LDS transpose; DS ops in-order per wave
  const int bl = lane >> 2, jq = lane & 3;
  const float* gr = g[wv*16 + bl];
  union { u16 h[4]; u64 q; } pk;
  #pragma unroll
  for (int jj = 0; jj < 4; ++jj){
    int cb = (jq*4 + jj)*4;
    float gi = gr[cb+0], gf = gr[cb+1], gg = gr[cb+2], go = gr[cb+3];
    float iv = 1.f/(1.f + expf(-gi));
    float fv = 1.f/(1.f + expf(-gf));
    float ov = 1.f/(1.f + expf(-go));
    float cn = fv*creg[jj] + iv*tanhf(gg);
    creg[jj] = cn;
    pk.h[jj] = f2b(ov * tanhf(cn));
  }
  // publish: agent store -> MALL (consumers acquire-fence then plain-load)
  stc64((u64*)(hdst + (mh*64 + wv*16 + bl)*512 + nt*16 + jq*4), pk.q);
}

// Flag protocol — IDENTICAL values to R7/R8 (flag = tau+1 after step tau;
// depth-4 rings, slot = tau&3; dec slot = s&3):
//  enc l0 t: f0>=t, f1>=t-3 | enc l1 u: f0>=u+1, f1>=u
//  dec l0 s: f0>=256+s, f1>=256+s | dec l1 s: f0>=257+s, f1>=256+s, fh>=s-2
//  heads: cls f1>=256 (slot 3) | forecast s: f1>=257+s (slot s&3)
// Consumer ordering: relaxed flag observation -> __syncthreads ->
// agent-acquire fence -> plain h loads (standard HIP acquire pattern).

__global__ __launch_bounds__(256, 1) __attribute__((amdgpu_waves_per_eu(1, 1)))
void persist_k(PK p){
  const int w = blockIdx.x, tid = threadIdx.x;
  const int wv = tid >> 6, lane = tid & 63;
  const long long t0 = wall_clock64();
  __shared__ float g[64][69];
  extern __shared__ u16 dynW[];
  unsigned* F = p.F;

  auto setflag = [&](int idx, unsigned val){
    __syncthreads();   // release: drains vmcnt (h stores) on every wave
    if (tid == 0) __hip_atomic_store(F + idx, val, __ATOMIC_RELAXED, SCOPE_AGENT);
  };
  auto acquire = [&](){
    __builtin_amdgcn_fence(__ATOMIC_ACQUIRE, "agent");  // invalidate stale L1/L2
  };

  if (w < 128){
    const int role = w >> 6;            // 0 = layer0 chain, 1 = layer1 chain
    const int q = w & 63;
    const int mh = q >> 5, nt = q & 31;
    const int fidx = role*64 + mh*32 + nt;
    u16* WA = dynW;
    u16* WB = dynW + 64*520;
    float creg[4] = {0.f,0.f,0.f,0.f};

    if (role == 0){
      { // preload: Wx0 slice (stride 40) + W0hh slice (stride 520)
        const unsigned* sA = (const unsigned*)(p.Wx0 + nt*64*32);
        unsigned* dA = (unsigned*)WA;
        for (int i = tid; i < 64*16; i += 256){ int r = i>>4, c = i&15; dA[r*20+c] = sA[r*16+c]; }
        const unsigned* sB = (const unsigned*)(p.W0hh + (size_t)nt*64*512);
        unsigned* dB = (unsigned*)WB;
        for (int i = tid; i < 64*256; i += 256){ int r = i>>8, c = i&255; dB[r*260+c] = sB[r*256+c]; }
      }
      const float* biasp = p.Bs + nt*64;
      __syncthreads();
      for (int t = 0; t < 256; ++t){
        if (wv == 0) pollF(F, mh, t, t-3, 0, t0);
        __syncthreads();
        acquire();
        lstm_step<1>(p.Xb + t*4096, 32, WA, 40,
                     p.h0b + ((t+3)&3)*HB, WB,
                     biasp, p.h0b + (t&3)*HB, creg, g, mh, nt, wv, lane);
        setflag(fidx, t+1);
      }
      { // reload decoder l0 weights (cell state stays in regs)
        const unsigned* sA = (const unsigned*)(p.Wd0ih + (size_t)nt*64*512);
        const unsigned* sB = (const unsigned*)(p.Wd0hh + (size_t)nt*64*512);
        unsigned* dA = (unsigned*)WA; unsigned* dB = (unsigned*)WB;
        for (int i = tid; i < 64*256; i += 256){
          int r = i>>8, c = i&255;
          dA[r*260+c] = sA[r*256+c]; dB[r*260+c] = sB[r*256+c];
        }
      }
      biasp = p.Bs + 4096 + nt*64;
      __syncthreads();
      for (int s = 0; s < 12; ++s){
        if (wv == 0) pollF(F, mh, 256+s, 256+s, 0, t0);
        __syncthreads();
        acquire();
        lstm_step<16>(p.h1b + ((s+3)&3)*HB, 512, WA, 520,
                      p.h0b + ((s+3)&3)*HB, WB,
                      biasp, p.h0b + (s&3)*HB, creg, g, mh, nt, wv, lane);
        setflag(fidx, 257+s);
      }
    } else {
      { // preload: W1ih + W1hh slices
        const unsigned* sA = (const unsigned*)(p.W1ih + (size_t)nt*64*512);
        const unsigned* sB = (const unsigned*)(p.W1hh + (size_t)nt*64*512);
        unsigned* dA = (unsigned*)WA; unsigned* dB = (unsigned*)WB;
        for (int i = tid; i < 64*256; i += 256){
          int r = i>>8, c = i&255;
          dA[r*260+c] = sA[r*256+c]; dB[r*260+c] = sB[r*256+c];
        }
      }
      const float* biasp = p.Bs + 2048 + nt*64;
      __syncthreads();
      for (int u = 0; u < 256; ++u){
        if (wv == 0) pollF(F, mh, u+1, u, 0, t0);
        __syncthreads();
        acquire();
        lstm_step<16>(p.h0b + (u&3)*HB, 512, WA, 520,
                      p.h1b + ((u+3)&3)*HB, WB,
                      biasp, p.h1b + (u&3)*HB, creg, g, mh, nt, wv, lane);
        setflag(fidx, u+1);
      }
      { // reload decoder l1 weights
        const unsigned* sA = (const unsigned*)(p.Wd1ih + (size_t)nt*64*512);
        const unsigned* sB = (const unsigned*)(p.Wd1hh + (size_t)nt*64*512);
        unsigned* dA = (unsigned*)WA; unsigned* dB = (unsigned*)WB;
        for (int i = tid; i < 64*256; i += 256){
          int r = i>>8, c = i&255;
          dA[r*260+c] = sA[r*256+c]; dB[r*260+c] = sB[r*256+c];
        }
      }
      biasp = p.Bs + 6144 + nt*64;
      __syncthreads();
      for (int s = 0; s < 12; ++s){
        if (wv == 0) pollF(F, mh, 257+s, 256+s, s-2, t0);   // heads WAR: fh>=s-2
        __syncthreads();
        acquire();
        lstm_step<16>(p.h0b + (s&3)*HB, 512, WA, 520,
                      p.h1b + ((s+3)&3)*HB, WB,
                      biasp, p.h1b + (s&3)*HB, creg, g, mh, nt, wv, lane);
        setflag(fidx, 257+s);
      }
    }
  } else if (w < 130){
    // ---- heads wg (one per mh half) — proven sc1/agent read path ----
    const int mh = w & 1;
    const int b = tid & 63, part = tid >> 6;
    const int gb = mh*64 + b;
    { // cls + reg from h1(255), ring slot 3 = 255&3
      if (wv == 0) pollF(F, mh, 0, 256, 0, t0);
      __syncthreads();
      const u64* hp = (const u64*)(p.h1b + 3*HB + gb*512 + part*128);
      float a[5] = {0.f,0.f,0.f,0.f,0.f};
      for (int c = 0; c < 32; ++c){
        u64 v = ldc64(hp + c);
        #pragma unroll
        for (int e = 0; e < 4; ++e){
          float hv = b2f((u16)(v >> (16*e)));
          int k = part*128 + c*4 + e;
          a[0] += hv * p.clsW[k];
          a[1] += hv * p.clsW[512 + k];
          a[2] += hv * p.clsW[1024 + k];
          a[3] += hv * p.clsW[1536 + k];
          a[4] += hv * p.regW[k];
        }
      }
      #pragma unroll
      for (int d = 0; d < 5; ++d) g[b][part*8 + d] = a[d];
      __syncthreads();
      if (tid < 64){
        #pragma unroll
        for (int d = 0; d < 5; ++d){
          float v = g[tid][d] + g[tid][8+d] + g[tid][16+d] + g[tid][24+d];
          if (d < 4) p.out[9216 + (mh*64 + tid)*4 + d] = v + p.clsb[d];
          else       p.out[9728 + mh*64 + tid]         = v + p.regb[0];
        }
      }
      __syncthreads();
      if (tid == 0) __hip_atomic_store(F + 128 + mh, 1u, __ATOMIC_RELAXED, SCOPE_AGENT);
    }
    for (int s = 0; s < 12; ++s){
      if (wv == 0) pollF(F, mh, 0, 257 + s, 0, t0);
      __syncthreads();
      // dec l1 writes h1(256+s) at slot (256+s)&3 = s&3
      const u64* hp = (const u64*)(p.h1b + (size_t)(s&3)*HB + gb*512 + part*128);
      float a[6] = {0.f,0.f,0.f,0.f,0.f,0.f};
      for (int c = 0; c < 32; ++c){
        u64 v = ldc64(hp + c);
        #pragma unroll
        for (int e = 0; e < 4; ++e){
          float hv = b2f((u16)(v >> (16*e)));
          int k = part*128 + c*4 + e;
          #pragma unroll
          for (int d = 0; d < 6; ++d) a[d] += hv * p.fcW[d*512 + k];
        }
      }
      #pragma unroll
      for (int d = 0; d < 6; ++d) g[b][part*8 + d] = a[d];
      __syncthreads();
      if (tid < 64){
        #pragma unroll
        for (int d = 0; d < 6; ++d){
          float v = g[tid][d] + g[tid][8+d] + g[tid][16+d] + g[tid][24+d];
          p.out[(mh*64 + tid)*72 + s*6 + d] = v + p.fcb[d];
        }
      }
      __syncthreads();
      if (tid == 0)
        __hip_atomic_store(F + 128 + mh, (unsigned)(s+2), __ATOMIC_RELAXED, SCOPE_AGENT);
    }
  }
}

// ---------------- launcher ----------------

extern "C" void kernel_launch(void* const* d_in, const int* in_sizes, int n_in,
                              void* d_out, int out_size, void* d_ws, size_t ws_size,
                              hipStream_t stream){
  const float* x     = (const float*)d_in[0];
  const float* eWih0 = (const float*)d_in[1];
  const float* eWhh0 = (const float*)d_in[2];
  const float* ebih0 = (const float*)d_in[3];
  const float* ebhh0 = (const float*)d_in[4];
  const float* eWih1 = (const float*)d_in[5];
  const float* eWhh1 = (const float*)d_in[6];
  const float* ebih1 = (const float*)d_in[7];
  const float* ebhh1 = (const float*)d_in[8];
  const float* dWih0 = (const float*)d_in[9];
  const float* dWhh0 = (const float*)d_in[10];
  const float* dbih0 = (const float*)d_in[11];
  const float* dbhh0 = (const float*)d_in[12];
  const float* dWih1 = (const float*)d_in[13];
  const float* dWhh1 = (const float*)d_in[14];
  const float* dbih1 = (const float*)d_in[15];
  const float* dbhh1 = (const float*)d_in[16];
  const float* fcW   = (const float*)d_in[17];
  const float* fcb   = (const float*)d_in[18];
  const float* clsW  = (const float*)d_in[19];
  const float* clsb  = (const float*)d_in[20];
  const float* regW  = (const float*)d_in[21];
  const float* regb  = (const float*)d_in[22];
  float* out = (float*)d_out;

  uintptr_t base = (uintptr_t)d_ws;
  auto carve = [&](size_t n)->void*{
    void* p = (void*)base; base += (n + 255) & ~(size_t)255; return p;
  };
  u16* Wx0b  = (u16*)carve(2048*32*2);
  u16* We0hh = (u16*)carve(2048*512*2);
  u16* We1ih = (u16*)carve(2048*512*2);
  u16* We1hh = (u16*)carve(2048*512*2);
  u16* Wd0ih = (u16*)carve(2048*512*2);
  u16* Wd0hh = (u16*)carve(2048*512*2);
  u16* Wd1ih = (u16*)carve(2048*512*2);
  u16* Wd1hh = (u16*)carve(2048*512*2);
  float* Bs  = (float*)carve(4*2048*4);
  u16* Xb    = (u16*)carve(256*128*32*2);
  u16* h0b   = (u16*)carve((size_t)4*HB*2);   // depth-4 ring, layer0
  u16* h1b   = (u16*)carve((size_t)4*HB*2);   // depth-4 ring, layer1
  unsigned* F = (unsigned*)carve(192*4);

  // zero h-rings + flags (contiguous 256-aligned carves)
  (void)hipMemsetAsync(h0b, 0, (size_t)4*HB*2 + (size_t)4*HB*2 + 768, stream);

  reorder_w_k<<<4096,256,0,stream>>>(eWhh0, We0hh);
  reorder_w_k<<<4096,256,0,stream>>>(eWih1, We1ih);
  reorder_w_k<<<4096,256,0,stream>>>(eWhh1, We1hh);
  reorder_w_k<<<4096,256,0,stream>>>(dWih0, Wd0ih);
  reorder_w_k<<<4096,256,0,stream>>>(dWhh0, Wd0hh);
  reorder_w_k<<<4096,256,0,stream>>>(dWih1, Wd1ih);
  reorder_w_k<<<4096,256,0,stream>>>(dWhh1, Wd1hh);
  prep_wx0_k<<<256,256,0,stream>>>(eWih0, Wx0b);
  prep_bias_k<<<8,256,0,stream>>>(ebih0, ebhh0, Bs);
  prep_bias_k<<<8,256,0,stream>>>(ebih1, ebhh1, Bs + 2048);
  prep_bias_k<<<8,256,0,stream>>>(dbih0, dbhh0, Bs + 4096);
  prep_bias_k<<<8,256,0,stream>>>(dbih1, dbhh1, Bs + 6144);
  prep_x_k<<<4096,256,0,stream>>>(x, Xb);

  PK p;
  p.Xb = Xb; p.Wx0 = Wx0b; p.W0hh = We0hh; p.W1ih = We1ih; p.W1hh = We1hh;
  p.Wd0ih = Wd0ih; p.Wd0hh = Wd0hh; p.Wd1ih = Wd1ih; p.Wd1hh = Wd1hh;
  p.Bs = Bs; p.h0b = h0b; p.h1b = h1b; p.F = F;
  p.fcW = fcW; p.fcb = fcb; p.clsW = clsW; p.clsb = clsb;
  p.regW = regW; p.regb = regb; p.out = out;

  const int dynLds = 2*64*520*2;   // 133,120 B (two 64x520 u16 weight slices)
  (void)hipFuncSetAttribute((const void*)persist_k,
                            hipFuncAttributeMaxDynamicSharedMemorySize, dynLds);

  void* args[] = { &p };
  hipError_t e = hipLaunchCooperativeKernel((const void*)persist_k, dim3(130), dim3(256),
                                            args, dynLds, stream);
  if (e != hipSuccess){
    // fallback: plain launch (130 wgs at 1 wg/CU are trivially co-resident;
    // poll deadline guards the pathological case)
    persist_k<<<dim3(130), dim3(256), dynLds, stream>>>(p);
  }
  (void)in_sizes; (void)n_in; (void)out_size; (void)ws_size;
}

// Round 12
// 2751.202 us; speedup vs baseline: 1.1922x; 1.1922x over previous
//
#include <hip/hip_runtime.h>
#include <hip/hip_bf16.h>

typedef __attribute__((ext_vector_type(8))) short short8;
typedef __attribute__((ext_vector_type(4))) float floatx4;
typedef unsigned short u16;
typedef unsigned long long u64;

#define SCOPE_AGENT __HIP_MEMORY_SCOPE_AGENT

// B=128, T=256, D=6, H=512, 4H=2048, NC=4, PS=12

__device__ __forceinline__ u16 f2b(float f){
  union { float fl; unsigned u; } v; v.fl = f;
  unsigned r = v.u + 0x7fffu + ((v.u >> 16) & 1u);   // RNE bf16
  return (u16)(r >> 16);
}
__device__ __forceinline__ float b2f(u16 b){
  union { unsigned u; float f; } v; v.u = ((unsigned)b) << 16; return v.f;
}

// ---- device-coherent (agent) primitives ----
// agent-scope load = `sc1` on gfx950. ldc8 = 16B-wide same coherence class
// (we need coherence, not 16B atomicity). ISSUE-ONLY: caller must
// s_waitcnt vmcnt(0) before consuming.
__device__ __forceinline__ short8 ldc8(const u16* p){
  short8 r;
  asm volatile("global_load_dwordx4 %0, %1, off sc1" : "=&v"(r) : "v"(p));
  return r;
}
__device__ __forceinline__ u64 ldc64(const u64* p){
  return __hip_atomic_load(p, __ATOMIC_RELAXED, SCOPE_AGENT);
}
__device__ __forceinline__ void stc64(u64* p, u64 v){
  __hip_atomic_store(p, v, __ATOMIC_RELAXED, SCOPE_AGENT);
}

// poll deadline (~0.5 s @ 100 MHz wall clock)
__device__ __forceinline__ bool expired(long long t0){
  return (wall_clock64() - t0) > 50000000LL;
}

// ---------------- prep kernels (R0 verbatim) ----------------

__global__ void reorder_w_k(const float* __restrict__ W, u16* __restrict__ out){
  int idx = blockIdx.x*256 + threadIdx.x;       // 2048*512
  int r = idx >> 9, k = idx & 511;
  int rp = ((r & 511) << 2) | (r >> 9);
  out[rp*512 + k] = f2b(W[idx]);
}
__global__ void prep_wx0_k(const float* __restrict__ W, u16* __restrict__ out){
  int idx = blockIdx.x*256 + threadIdx.x;       // 2048*32
  int r = idx >> 5, k = idx & 31;
  int rp = ((r & 511) << 2) | (r >> 9);
  out[rp*32 + k] = (k < 6) ? f2b(W[r*6 + k]) : (u16)0;
}
__global__ void prep_bias_k(const float* __restrict__ bih, const float* __restrict__ bhh,
                            float* __restrict__ out){
  int r = blockIdx.x*256 + threadIdx.x;         // 2048
  int rp = ((r & 511) << 2) | (r >> 9);
  out[rp] = bih[r] + bhh[r];
}
__global__ void prep_x_k(const float* __restrict__ x, u16* __restrict__ out){
  int idx = blockIdx.x*256 + threadIdx.x;       // 256*128*32
  int t = idx >> 12; int rem = idx & 4095; int b = rem >> 5; int k = rem & 31;
  out[idx] = (k < 6) ? f2b(x[(b*256 + t)*6 + k]) : (u16)0;
}

// ---------------- persistent LSTM kernel ----------------

struct PK {
  const u16 *Xb, *Wx0, *W0hh, *W1ih, *W1hh, *Wd0ih, *Wd0hh, *Wd1ih, *Wd1hh;
  const float *Bs;              // 4x2048 gate-interleaved biases
  u16 *h0b, *h1b;               // bf16 DEPTH-4 h rings [4][128][512], slot = tau&3
  unsigned *F;                  // [0..63]=l0 (mh*32+nt), [64..127]=l1, [128..129]=heads
  const float *fcW, *fcb, *clsW, *clsb, *regW, *regb;
  float *out;
};

#define HB 65536   // u16 elements per ring slot (128 x 512)

// flag poll — wave 0 only (callers barrier afterwards). BOUNDED HOT SPIN
// (R12): first 2048 iterations spin without sleep (steady-state flags land
// inside this window -> no sleep quantization / idle-downclock signal on the
// fast path); afterwards gentle s_sleep(1) backoff (prologue / stragglers).
// Deadline check amortized (s_memtime serializes).
__device__ __forceinline__ void pollF(const unsigned* F, int mh, int thr0, int thr1,
                                      int thrh, long long t0){
  const int lane = threadIdx.x & 63;
  const unsigned* ap = (lane < 32) ? (F + mh*32 + lane) : (F + 64 + mh*32 + (lane - 32));
  const int thr = (lane < 32) ? thr0 : thr1;
  int iter = 0;
  for(;;){
    int v = (int)__hip_atomic_load(ap, __ATOMIC_RELAXED, SCOPE_AGENT);
    bool ok = (v >= thr);
    if (thrh > 0 && lane == 0)
      ok = ok && ((int)__hip_atomic_load(F + 128 + mh, __ATOMIC_RELAXED, SCOPE_AGENT) >= thrh);
    if (__all(ok)) return;
    ++iter;
    if ((iter & 63) == 0 && expired(t0)) return;
    if (iter > 2048) __builtin_amdgcn_s_sleep(1);
  }
}

// One LSTM step tile for wg (role, mh, nt): 64 batches x 64 gates (R0-proven).
// Coherent A loads are issue-only dwordx4 sc1; one vmcnt(0) drains them all.
template<int NK1, bool COH1>
__device__ __forceinline__ void lstm_step(
    const u16* __restrict__ A1, int a1rowlen, const u16* __restrict__ ldsW1, int st1,
    const u16* __restrict__ A2, const u16* __restrict__ ldsW2,
    const float* __restrict__ biasp, u16* __restrict__ hdst,
    float* creg, float (*g)[69],
    int mh, int nt, int wv, int lane)
{
  const int lrow = lane & 15, kq = lane >> 4;
  const int arow = mh*64 + wv*16 + lrow;
  short8 a1[NK1], a2[16];
  {
    const u16* p1 = A1 + arow*a1rowlen + kq*8;
    #pragma unroll
    for (int k = 0; k < NK1; ++k)
      a1[k] = COH1 ? ldc8(p1 + k*32) : *(const short8*)(p1 + k*32);
    const u16* p2 = A2 + arow*512 + kq*8;
    #pragma unroll
    for (int k = 0; k < 16; ++k) a2[k] = ldc8(p2 + k*32);
  }
  asm volatile("s_waitcnt vmcnt(0)" ::: "memory");   // drain issue-only sc1 loads
  __builtin_amdgcn_sched_barrier(0);                  // rule #18: keep MFMAs below
  floatx4 acc[4];
  #pragma unroll
  for (int nn = 0; nn < 4; ++nn) acc[nn] = (floatx4){0.f,0.f,0.f,0.f};
  #pragma unroll
  for (int nn = 0; nn < 4; ++nn){
    const u16* wb = ldsW1 + (nn*16 + lrow)*st1 + kq*8;
    #pragma unroll
    for (int k = 0; k < NK1; ++k)
      acc[nn] = __builtin_amdgcn_mfma_f32_16x16x32_bf16(a1[k], *(const short8*)(wb + k*32), acc[nn], 0,0,0);
  }
  #pragma unroll
  for (int nn = 0; nn < 4; ++nn){
    const u16* wb = ldsW2 + (nn*16 + lrow)*520 + kq*8;
    #pragma unroll
    for (int k = 0; k < 16; ++k)
      acc[nn] = __builtin_amdgcn_mfma_f32_16x16x32_bf16(a2[k], *(const short8*)(wb + k*32), acc[nn], 0,0,0);
  }
  // C/D layout: row(m) = kq*4 + r, col(n) = lane&15 -> g rows wv*16..+15 only
  #pragma unroll
  for (int nn = 0; nn < 4; ++nn){
    float bn = biasp[nn*16 + lrow];
    #pragma unroll
    for (int r = 0; r < 4; ++r)
      g[wv*16 + kq*4 + r][nn*16 + lrow] = acc[nn][r] + bn;
  }
  __builtin_amdgcn_wave_barrier();   // intra-wave LDS transpose; DS ops in-order per wave
  const int bl = lane >> 2, jq = lane & 3;
  const float* gr = g[wv*16 + bl];
  union { u16 h[4]; u64 q; } pk;
  #pragma unroll
  for (int jj = 0; jj < 4; ++jj){
    int cb = (jq*4 + jj)*4;
    float gi = gr[cb+0], gf = gr[cb+1], gg = gr[cb+2], go = gr[cb+3];
    float iv = 1.f/(1.f + expf(-gi));
    float fv = 1.f/(1.f + expf(-gf));
    float ov = 1.f/(1.f + expf(-go));
    float cn = fv*creg[jj] + iv*tanhf(gg);
    creg[jj] = cn;
    pk.h[jj] = f2b(ov * tanhf(cn));
  }
  stc64((u64*)(hdst + (mh*64 + wv*16 + bl)*512 + nt*16 + jq*4), pk.q);
}

// Flag protocol — IDENTICAL to R8 (flag = tau+1 after step tau; depth-4
// rings, slot = tau&3; dec slot = s&3):
//  enc l0 t: f0>=t, f1>=t-3 | enc l1 u: f0>=u+1, f1>=u
//  dec l0 s: f0>=256+s, f1>=256+s | dec l1 s: f0>=257+s, f1>=256+s, fh>=s-2
//  heads: cls f1>=256 (slot 3) | forecast s: f1>=257+s (slot s&3)

__global__ __launch_bounds__(256, 1) __attribute__((amdgpu_waves_per_eu(1, 1)))
void persist_k(PK p){
  const int w = blockIdx.x, tid = threadIdx.x;
  const int wv = tid >> 6, lane = tid & 63;
  const long long t0 = wall_clock64();
  __shared__ float g[64][69];
  extern __shared__ u16 dynW[];
  unsigned* F = p.F;

  auto setflag = [&](int idx, unsigned val){
    __syncthreads();   // release: drains vmcnt (h stores) on every wave
    if (tid == 0) __hip_atomic_store(F + idx, val, __ATOMIC_RELAXED, SCOPE_AGENT);
  };

  if (w < 128){
    const int role = w >> 6;            // 0 = layer0 chain, 1 = layer1 chain
    const int q = w & 63;
    const int mh = q >> 5, nt = q & 31;
    const int fidx = role*64 + mh*32 + nt;
    u16* WA = dynW;
    u16* WB = dynW + 64*520;
    float creg[4] = {0.f,0.f,0.f,0.f};

    if (role == 0){
      { // preload: Wx0 slice (stride 40) + W0hh slice (stride 520)
        const unsigned* sA = (const unsigned*)(p.Wx0 + nt*64*32);
        unsigned* dA = (unsigned*)WA;
        for (int i = tid; i < 64*16; i += 256){ int r = i>>4, c = i&15; dA[r*20+c] = sA[r*16+c]; }
        const unsigned* sB = (const unsigned*)(p.W0hh + (size_t)nt*64*512);
        unsigned* dB = (unsigned*)WB;
        for (int i = tid; i < 64*256; i += 256){ int r = i>>8, c = i&255; dB[r*260+c] = sB[r*256+c]; }
      }
      const float* biasp = p.Bs + nt*64;
      __syncthreads();
      for (int t = 0; t < 256; ++t){
        if (wv == 0) pollF(F, mh, t, t-3, 0, t0);
        __syncthreads();
        lstm_step<1,false>(p.Xb + t*4096, 32, WA, 40,
                           p.h0b + ((t+3)&3)*HB, WB,
                           biasp, p.h0b + (t&3)*HB, creg, g, mh, nt, wv, lane);
        setflag(fidx, t+1);
      }
      { // reload decoder l0 weights (cell state stays in regs)
        const unsigned* sA = (const unsigned*)(p.Wd0ih + (size_t)nt*64*512);
        const unsigned* sB = (const unsigned*)(p.Wd0hh + (size_t)nt*64*512);
        unsigned* dA = (unsigned*)WA; unsigned* dB = (unsigned*)WB;
        for (int i = tid; i < 64*256; i += 256){
          int r = i>>8, c = i&255;
          dA[r*260+c] = sA[r*256+c]; dB[r*260+c] = sB[r*256+c];
        }
      }
      biasp = p.Bs + 4096 + nt*64;
      __syncthreads();
      for (int s = 0; s < 12; ++s){
        if (wv == 0) pollF(F, mh, 256+s, 256+s, 0, t0);
        __syncthreads();
        lstm_step<16,true>(p.h1b + ((s+3)&3)*HB, 512, WA, 520,
                           p.h0b + ((s+3)&3)*HB, WB,
                           biasp, p.h0b + (s&3)*HB, creg, g, mh, nt, wv, lane);
        setflag(fidx, 257+s);
      }
    } else {
      { // preload: W1ih + W1hh slices
        const unsigned* sA = (const unsigned*)(p.W1ih + (size_t)nt*64*512);
        const unsigned* sB = (const unsigned*)(p.W1hh + (size_t)nt*64*512);
        unsigned* dA = (unsigned*)WA; unsigned* dB = (unsigned*)WB;
        for (int i = tid; i < 64*256; i += 256){
          int r = i>>8, c = i&255;
          dA[r*260+c] = sA[r*256+c]; dB[r*260+c] = sB[r*256+c];
        }
      }
      const float* biasp = p.Bs + 2048 + nt*64;
      __syncthreads();
      for (int u = 0; u < 256; ++u){
        if (wv == 0) pollF(F, mh, u+1, u, 0, t0);
        __syncthreads();
        lstm_step<16,true>(p.h0b + (u&3)*HB, 512, WA, 520,
                           p.h1b + ((u+3)&3)*HB, WB,
                           biasp, p.h1b + (u&3)*HB, creg, g, mh, nt, wv, lane);
        setflag(fidx, u+1);
      }
      { // reload decoder l1 weights
        const unsigned* sA = (const unsigned*)(p.Wd1ih + (size_t)nt*64*512);
        const unsigned* sB = (const unsigned*)(p.Wd1hh + (size_t)nt*64*512);
        unsigned* dA = (unsigned*)WA; unsigned* dB = (unsigned*)WB;
        for (int i = tid; i < 64*256; i += 256){
          int r = i>>8, c = i&255;
          dA[r*260+c] = sA[r*256+c]; dB[r*260+c] = sB[r*256+c];
        }
      }
      biasp = p.Bs + 6144 + nt*64;
      __syncthreads();
      for (int s = 0; s < 12; ++s){
        if (wv == 0) pollF(F, mh, 257+s, 256+s, s-2, t0);   // heads WAR: fh>=s-2
        __syncthreads();
        lstm_step<16,true>(p.h0b + (s&3)*HB, 512, WA, 520,
                           p.h1b + ((s+3)&3)*HB, WB,
                           biasp, p.h1b + (s&3)*HB, creg, g, mh, nt, wv, lane);
        setflag(fidx, 257+s);
      }
    }
  } else if (w < 130){
    // ---- heads wg (one per mh half) ----
    const int mh = w & 1;
    const int b = tid & 63, part = tid >> 6;
    const int gb = mh*64 + b;
    { // cls + reg from h1(255), ring slot 3 = 255&3
      if (wv == 0) pollF(F, mh, 0, 256, 0, t0);
      __syncthreads();
      const u64* hp = (const u64*)(p.h1b + 3*HB + gb*512 + part*128);
      float a[5] = {0.f,0.f,0.f,0.f,0.f};
      for (int c = 0; c < 32; ++c){
        u64 v = ldc64(hp + c);
        #pragma unroll
        for (int e = 0; e < 4; ++e){
          float hv = b2f((u16)(v >> (16*e)));
          int k = part*128 + c*4 + e;
          a[0] += hv * p.clsW[k];
          a[1] += hv * p.clsW[512 + k];
          a[2] += hv * p.clsW[1024 + k];
          a[3] += hv * p.clsW[1536 + k];
          a[4] += hv * p.regW[k];
        }
      }
      #pragma unroll
      for (int d = 0; d < 5; ++d) g[b][part*8 + d] = a[d];
      __syncthreads();
      if (tid < 64){
        #pragma unroll
        for (int d = 0; d < 5; ++d){
          float v = g[tid][d] + g[tid][8+d] + g[tid][16+d] + g[tid][24+d];
          if (d < 4) p.out[9216 + (mh*64 + tid)*4 + d] = v + p.clsb[d];
          else       p.out[9728 + mh*64 + tid]         = v + p.regb[0];
        }
      }
      __syncthreads();
      if (tid == 0) __hip_atomic_store(F + 128 + mh, 1u, __ATOMIC_RELAXED, SCOPE_AGENT);
    }
    for (int s = 0; s < 12; ++s){
      if (wv == 0) pollF(F, mh, 0, 257 + s, 0, t0);
      __syncthreads();
      // dec l1 writes h1(256+s) at slot (256+s)&3 = s&3
      const u64* hp = (const u64*)(p.h1b + (size_t)(s&3)*HB + gb*512 + part*128);
      float a[6] = {0.f,0.f,0.f,0.f,0.f,0.f};
      for (int c = 0; c < 32; ++c){
        u64 v = ldc64(hp + c);
        #pragma unroll
        for (int e = 0; e < 4; ++e){
          float hv = b2f((u16)(v >> (16*e)));
          int k = part*128 + c*4 + e;
          #pragma unroll
          for (int d = 0; d < 6; ++d) a[d] += hv * p.fcW[d*512 + k];
        }
      }
      #pragma unroll
      for (int d = 0; d < 6; ++d) g[b][part*8 + d] = a[d];
      __syncthreads();
      if (tid < 64){
        #pragma unroll
        for (int d = 0; d < 6; ++d){
          float v = g[tid][d] + g[tid][8+d] + g[tid][16+d] + g[tid][24+d];
          p.out[(mh*64 + tid)*72 + s*6 + d] = v + p.fcb[d];
        }
      }
      __syncthreads();
      if (tid == 0)
        __hip_atomic_store(F + 128 + mh, (unsigned)(s+2), __ATOMIC_RELAXED, SCOPE_AGENT);
    }
  }
}

// ---------------- launcher ----------------

extern "C" void kernel_launch(void* const* d_in, const int* in_sizes, int n_in,
                              void* d_out, int out_size, void* d_ws, size_t ws_size,
                              hipStream_t stream){
  const float* x     = (const float*)d_in[0];
  const float* eWih0 = (const float*)d_in[1];
  const float* eWhh0 = (const float*)d_in[2];
  const float* ebih0 = (const float*)d_in[3];
  const float* ebhh0 = (const float*)d_in[4];
  const float* eWih1 = (const float*)d_in[5];
  const float* eWhh1 = (const float*)d_in[6];
  const float* ebih1 = (const float*)d_in[7];
  const float* ebhh1 = (const float*)d_in[8];
  const float* dWih0 = (const float*)d_in[9];
  const float* dWhh0 = (const float*)d_in[10];
  const float* dbih0 = (const float*)d_in[11];
  const float* dbhh0 = (const float*)d_in[12];
  const float* dWih1 = (const float*)d_in[13];
  const float* dWhh1 = (const float*)d_in[14];
  const float* dbih1 = (const float*)d_in[15];
  const float* dbhh1 = (const float*)d_in[16];
  const float* fcW   = (const float*)d_in[17];
  const float* fcb   = (const float*)d_in[18];
  const float* clsW  = (const float*)d_in[19];
  const float* clsb  = (const float*)d_in[20];
  const float* regW  = (const float*)d_in[21];
  const float* regb  = (const float*)d_in[22];
  float* out = (float*)d_out;

  uintptr_t base = (uintptr_t)d_ws;
  auto carve = [&](size_t n)->void*{
    void* p = (void*)base; base += (n + 255) & ~(size_t)255; return p;
  };
  u16* Wx0b  = (u16*)carve(2048*32*2);
  u16* We0hh = (u16*)carve(2048*512*2);
  u16* We1ih = (u16*)carve(2048*512*2);
  u16* We1hh = (u16*)carve(2048*512*2);
  u16* Wd0ih = (u16*)carve(2048*512*2);
  u16* Wd0hh = (u16*)carve(2048*512*2);
  u16* Wd1ih = (u16*)carve(2048*512*2);
  u16* Wd1hh = (u16*)carve(2048*512*2);
  float* Bs  = (float*)carve(4*2048*4);
  u16* Xb    = (u16*)carve(256*128*32*2);
  u16* h0b   = (u16*)carve((size_t)4*HB*2);   // depth-4 ring, layer0
  u16* h1b   = (u16*)carve((size_t)4*HB*2);   // depth-4 ring, layer1
  unsigned* F = (unsigned*)carve(192*4);

  // zero h-rings + flags (contiguous 256-aligned carves)
  (void)hipMemsetAsync(h0b, 0, (size_t)4*HB*2 + (size_t)4*HB*2 + 768, stream);

  reorder_w_k<<<4096,256,0,stream>>>(eWhh0, We0hh);
  reorder_w_k<<<4096,256,0,stream>>>(eWih1, We1ih);
  reorder_w_k<<<4096,256,0,stream>>>(eWhh1, We1hh);
  reorder_w_k<<<4096,256,0,stream>>>(dWih0, Wd0ih);
  reorder_w_k<<<4096,256,0,stream>>>(dWhh0, Wd0hh);
  reorder_w_k<<<4096,256,0,stream>>>(dWih1, Wd1ih);
  reorder_w_k<<<4096,256,0,stream>>>(dWhh1, Wd1hh);
  prep_wx0_k<<<256,256,0,stream>>>(eWih0, Wx0b);
  prep_bias_k<<<8,256,0,stream>>>(ebih0, ebhh0, Bs);
  prep_bias_k<<<8,256,0,stream>>>(ebih1, ebhh1, Bs + 2048);
  prep_bias_k<<<8,256,0,stream>>>(dbih0, dbhh0, Bs + 4096);
  prep_bias_k<<<8,256,0,stream>>>(dbih1, dbhh1, Bs + 6144);
  prep_x_k<<<4096,256,0,stream>>>(x, Xb);

  PK p;
  p.Xb = Xb; p.Wx0 = Wx0b; p.W0hh = We0hh; p.W1ih = We1ih; p.W1hh = We1hh;
  p.Wd0ih = Wd0ih; p.Wd0hh = Wd0hh; p.Wd1ih = Wd1ih; p.Wd1hh = Wd1hh;
  p.Bs = Bs; p.h0b = h0b; p.h1b = h1b; p.F = F;
  p.fcW = fcW; p.fcb = fcb; p.clsW = clsW; p.clsb = clsb;
  p.regW = regW; p.regb = regb; p.out = out;

  const int dynLds = 2*64*520*2;   // 133,120 B (two 64x520 u16 weight slices)
  (void)hipFuncSetAttribute((const void*)persist_k,
                            hipFuncAttributeMaxDynamicSharedMemorySize, dynLds);

  void* args[] = { &p };
  hipError_t e = hipLaunchCooperativeKernel((const void*)persist_k, dim3(130), dim3(256),
                                            args, dynLds, stream);
  if (e != hipSuccess){
    // fallback: plain launch (130 wgs at 1 wg/CU are trivially co-resident;
    // poll deadline guards the pathological case)
    persist_k<<<dim3(130), dim3(256), dynLds, stream>>>(p);
  }
  (void)in_sizes; (void)n_in; (void)out_size; (void)ws_size;
}

// Round 14
// 2720.688 us; speedup vs baseline: 1.2055x; 1.0112x over previous
//
#include <hip/hip_runtime.h>
#include <hip/hip_bf16.h>

typedef __attribute__((ext_vector_type(8))) short short8;
typedef __attribute__((ext_vector_type(4))) float floatx4;
typedef unsigned short u16;
typedef unsigned long long u64;

#define SCOPE_AGENT __HIP_MEMORY_SCOPE_AGENT

// B=128, T=256, D=6, H=512, 4H=2048, NC=4, PS=12

__device__ __forceinline__ u16 f2b(float f){
  union { float fl; unsigned u; } v; v.fl = f;
  unsigned r = v.u + 0x7fffu + ((v.u >> 16) & 1u);   // RNE bf16
  return (u16)(r >> 16);
}
__device__ __forceinline__ float b2f(u16 b){
  union { unsigned u; float f; } v; v.u = ((unsigned)b) << 16; return v.f;
}

// ---- device-coherent (agent) primitives ----
// agent-scope load = `sc1` on gfx950. ldc8 = 16B-wide same coherence class.
// ISSUE-ONLY: caller must s_waitcnt vmcnt(0) before consuming.
__device__ __forceinline__ short8 ldc8(const u16* p){
  short8 r;
  asm volatile("global_load_dwordx4 %0, %1, off sc1" : "=&v"(r) : "v"(p));
  return r;
}
__device__ __forceinline__ u64 ldc64(const u64* p){
  return __hip_atomic_load(p, __ATOMIC_RELAXED, SCOPE_AGENT);
}
__device__ __forceinline__ void stc64(u64* p, u64 v){
  __hip_atomic_store(p, v, __ATOMIC_RELAXED, SCOPE_AGENT);
}

// poll deadline (~0.5 s @ 100 MHz wall clock)
__device__ __forceinline__ bool expired(long long t0){
  return (wall_clock64() - t0) > 50000000LL;
}

// ---------------- prep kernels (R0 verbatim) ----------------

__global__ void reorder_w_k(const float* __restrict__ W, u16* __restrict__ out){
  int idx = blockIdx.x*256 + threadIdx.x;       // 2048*512
  int r = idx >> 9, k = idx & 511;
  int rp = ((r & 511) << 2) | (r >> 9);
  out[rp*512 + k] = f2b(W[idx]);
}
__global__ void prep_wx0_k(const float* __restrict__ W, u16* __restrict__ out){
  int idx = blockIdx.x*256 + threadIdx.x;       // 2048*32
  int r = idx >> 5, k = idx & 31;
  int rp = ((r & 511) << 2) | (r >> 9);
  out[rp*32 + k] = (k < 6) ? f2b(W[r*6 + k]) : (u16)0;
}
__global__ void prep_bias_k(const float* __restrict__ bih, const float* __restrict__ bhh,
                            float* __restrict__ out){
  int r = blockIdx.x*256 + threadIdx.x;         // 2048
  int rp = ((r & 511) << 2) | (r >> 9);
  out[rp] = bih[r] + bhh[r];
}
__global__ void prep_x_k(const float* __restrict__ x, u16* __restrict__ out){
  int idx = blockIdx.x*256 + threadIdx.x;       // 256*128*32
  int t = idx >> 12; int rem = idx & 4095; int b = rem >> 5; int k = rem & 31;
  out[idx] = (k < 6) ? f2b(x[(b*256 + t)*6 + k]) : (u16)0;
}

// ---------------- persistent LSTM kernel ----------------

struct PK {
  const u16 *Xb, *Wx0, *W0hh, *W1ih, *W1hh, *Wd0ih, *Wd0hh, *Wd1ih, *Wd1hh;
  const float *Bs;              // 4x2048 gate-interleaved biases
  u16 *h0b, *h1b;               // bf16 h rings; slot layout depends on DEEP
  unsigned *F;                  // [0..63]=l0 (mh*32+nt), [64..127]=l1, [128..129]=heads
  const float *fcW, *fcb, *clsW, *clsb, *regW, *regb;
  float *out;
};

#define HB 65536      // u16 elements per ring slot (128 x 512)
#define NSLOT 269     // deep ring: one slot per h(tau), tau = -1..267

// flag poll — wave 0 only (callers barrier afterwards). R8-proven form.
__device__ __forceinline__ void pollF(const unsigned* F, int mh, int thr0, int thr1,
                                      int thrh, long long t0){
  const int lane = threadIdx.x & 63;
  const unsigned* ap = (lane < 32) ? (F + mh*32 + lane) : (F + 64 + mh*32 + (lane - 32));
  const int thr = (lane < 32) ? thr0 : thr1;
  for(;;){
    int v = (int)__hip_atomic_load(ap, __ATOMIC_RELAXED, SCOPE_AGENT);
    bool ok = (v >= thr);
    if (thrh > 0 && lane == 0)
      ok = ok && ((int)__hip_atomic_load(F + 128 + mh, __ATOMIC_RELAXED, SCOPE_AGENT) >= thrh);
    if (__all(ok)) return;
    if (expired(t0)) return;
    if (__any((thr - v) > 2)) __builtin_amdgcn_s_sleep(16);
    else                      __builtin_amdgcn_s_sleep(1);
  }
}

// One LSTM step tile for wg (role, mh, nt): 64 batches x 64 gates (R0-proven).
// COH1/COH2 select sc1 (shallow rings: coherent MALL read required) vs plain
// cached loads (deep rings: address written exactly once before its flag ->
// no stale-line hazard; co-XCD wgs share the line via L2 = broadcast dedup).
template<int NK1, bool COH1, bool COH2>
__device__ __forceinline__ void lstm_step(
    const u16* __restrict__ A1, int a1rowlen, const u16* __restrict__ ldsW1, int st1,
    const u16* __restrict__ A2, const u16* __restrict__ ldsW2,
    const float* __restrict__ biasp, u16* __restrict__ hdst,
    float* creg, float (*g)[69],
    int mh, int nt, int wv, int lane)
{
  const int lrow = lane & 15, kq = lane >> 4;
  const int arow = mh*64 + wv*16 + lrow;
  short8 a1[NK1], a2[16];
  {
    const u16* p1 = A1 + arow*a1rowlen + kq*8;
    #pragma unroll
    for (int k = 0; k < NK1; ++k)
      a1[k] = COH1 ? ldc8(p1 + k*32) : *(const short8*)(p1 + k*32);
    const u16* p2 = A2 + arow*512 + kq*8;
    #pragma unroll
    for (int k = 0; k < 16; ++k)
      a2[k] = COH2 ? ldc8(p2 + k*32) : *(const short8*)(p2 + k*32);
  }
  asm volatile("s_waitcnt vmcnt(0)" ::: "memory");   // drain issue-only sc1 loads
  __builtin_amdgcn_sched_barrier(0);                  // rule #18: keep MFMAs below
  floatx4 acc[4];
  #pragma unroll
  for (int nn = 0; nn < 4; ++nn) acc[nn] = (floatx4){0.f,0.f,0.f,0.f};
  #pragma unroll
  for (int nn = 0; nn < 4; ++nn){
    const u16* wb = ldsW1 + (nn*16 + lrow)*st1 + kq*8;
    #pragma unroll
    for (int k = 0; k < NK1; ++k)
      acc[nn] = __builtin_amdgcn_mfma_f32_16x16x32_bf16(a1[k], *(const short8*)(wb + k*32), acc[nn], 0,0,0);
  }
  #pragma unroll
  for (int nn = 0; nn < 4; ++nn){
    const u16* wb = ldsW2 + (nn*16 + lrow)*520 + kq*8;
    #pragma unroll
    for (int k = 0; k < 16; ++k)
      acc[nn] = __builtin_amdgcn_mfma_f32_16x16x32_bf16(a2[k], *(const short8*)(wb + k*32), acc[nn], 0,0,0);
  }
  // C/D layout: row(m) = kq*4 + r, col(n) = lane&15 -> g rows wv*16..+15 only
  #pragma unroll
  for (int nn = 0; nn < 4; ++nn){
    float bn = biasp[nn*16 + lrow];
    #pragma unroll
    for (int r = 0; r < 4; ++r)
      g[wv*16 + kq*4 + r][nn*16 + lrow] = acc[nn][r] + bn;
  }
  __builtin_amdgcn_wave_barrier();   // intra-wave LDS transpose; DS ops in-order per wave
  const int bl = lane >> 2, jq = lane & 3;
  const float* gr = g[wv*16 + bl];
  union { u16 h[4]; u64 q; } pk;
  #pragma unroll
  for (int jj = 0; jj < 4; ++jj){
    int cb = (jq*4 + jj)*4;
    float gi = gr[cb+0], gf = gr[cb+1], gg = gr[cb+2], go = gr[cb+3];
    float iv = 1.f/(1.f + expf(-gi));
    float fv = 1.f/(1.f + expf(-gf));
    float ov = 1.f/(1.f + expf(-go));
    float cn = fv*creg[jj] + iv*tanhf(gg);
    creg[jj] = cn;
    pk.h[jj] = f2b(ov * tanhf(cn));
  }
  // publish: sc1 -> MALL (drained before flag in setflag)
  stc64((u64*)(hdst + (mh*64 + wv*16 + bl)*512 + nt*16 + jq*4), pk.q);
}

// Flag protocol — IDENTICAL to R8 (flag = tau+1 after step tau):
//  enc l0 t: f0>=t, f1>=t-3 | enc l1 u: f0>=u+1, f1>=u
//  dec l0 s: f0>=256+s, f1>=256+s | dec l1 s: f0>=257+s, f1>=256+s, fh>=s-2
//  heads: cls f1>=256 | forecast s: f1>=257+s
// Ring slot for h(tau): DEEP ? tau+1 (no reuse, 269 slots, slot 0 = zeros)
//                            : tau&3 (depth-4; reduces to R8's masks exactly)

template<bool DEEP>
__global__ __launch_bounds__(256, 1) __attribute__((amdgpu_waves_per_eu(1, 1)))
void persist_k(PK p){
  const int w = blockIdx.x, tid = threadIdx.x;
  const int wv = tid >> 6, lane = tid & 63;
  const long long t0 = wall_clock64();
  __shared__ float g[64][69];
  extern __shared__ u16 dynW[];
  unsigned* F = p.F;
  constexpr bool HC = !DEEP;   // h loads coherent (sc1) only in shallow mode

  auto hslot = [](int tt)->size_t { return DEEP ? (size_t)(tt + 1) : (size_t)(tt & 3); };

  auto setflag = [&](int idx, unsigned val){
    __syncthreads();   // release: drains vmcnt (h stores) on every wave
    if (tid == 0) __hip_atomic_store(F + idx, val, __ATOMIC_RELAXED, SCOPE_AGENT);
  };

  if (w < 128){
    const int role = w >> 6;            // 0 = layer0 chain, 1 = layer1 chain
    const int q = w & 63;
    const int mh = q >> 5, nt = q & 31;
    const int fidx = role*64 + mh*32 + nt;
    u16* WA = dynW;
    u16* WB = dynW + 64*520;
    float creg[4] = {0.f,0.f,0.f,0.f};

    if (role == 0){
      { // preload: Wx0 slice (stride 40) + W0hh slice (stride 520)
        const unsigned* sA = (const unsigned*)(p.Wx0 + nt*64*32);
        unsigned* dA = (unsigned*)WA;
        for (int i = tid; i < 64*16; i += 256){ int r = i>>4, c = i&15; dA[r*20+c] = sA[r*16+c]; }
        const unsigned* sB = (const unsigned*)(p.W0hh + (size_t)nt*64*512);
        unsigned* dB = (unsigned*)WB;
        for (int i = tid; i < 64*256; i += 256){ int r = i>>8, c = i&255; dB[r*260+c] = sB[r*256+c]; }
      }
      const float* biasp = p.Bs + nt*64;
      __syncthreads();
      for (int t = 0; t < 256; ++t){
        if (wv == 0) pollF(F, mh, t, t-3, 0, t0);
        __syncthreads();
        lstm_step<1,false,HC>(p.Xb + t*4096, 32, WA, 40,
                              p.h0b + hslot(t-1)*HB, WB,
                              biasp, p.h0b + hslot(t)*HB, creg, g, mh, nt, wv, lane);
        setflag(fidx, t+1);
      }
      { // reload decoder l0 weights (cell state stays in regs)
        const unsigned* sA = (const unsigned*)(p.Wd0ih + (size_t)nt*64*512);
        const unsigned* sB = (const unsigned*)(p.Wd0hh + (size_t)nt*64*512);
        unsigned* dA = (unsigned*)WA; unsigned* dB = (unsigned*)WB;
        for (int i = tid; i < 64*256; i += 256){
          int r = i>>8, c = i&255;
          dA[r*260+c] = sA[r*256+c]; dB[r*260+c] = sB[r*256+c];
        }
      }
      biasp = p.Bs + 4096 + nt*64;
      __syncthreads();
      for (int s = 0; s < 12; ++s){
        if (wv == 0) pollF(F, mh, 256+s, 256+s, 0, t0);
        __syncthreads();
        lstm_step<16,HC,HC>(p.h1b + hslot(255+s)*HB, 512, WA, 520,
                            p.h0b + hslot(255+s)*HB, WB,
                            biasp, p.h0b + hslot(256+s)*HB, creg, g, mh, nt, wv, lane);
        setflag(fidx, 257+s);
      }
    } else {
      { // preload: W1ih + W1hh slices
        const unsigned* sA = (const unsigned*)(p.W1ih + (size_t)nt*64*512);
        const unsigned* sB = (const unsigned*)(p.W1hh + (size_t)nt*64*512);
        unsigned* dA = (unsigned*)WA; unsigned* dB = (unsigned*)WB;
        for (int i = tid; i < 64*256; i += 256){
          int r = i>>8, c = i&255;
          dA[r*260+c] = sA[r*256+c]; dB[r*260+c] = sB[r*256+c];
        }
      }
      const float* biasp = p.Bs + 2048 + nt*64;
      __syncthreads();
      for (int u = 0; u < 256; ++u){
        if (wv == 0) pollF(F, mh, u+1, u, 0, t0);
        __syncthreads();
        lstm_step<16,HC,HC>(p.h0b + hslot(u)*HB, 512, WA, 520,
                            p.h1b + hslot(u-1)*HB, WB,
                            biasp, p.h1b + hslot(u)*HB, creg, g, mh, nt, wv, lane);
        setflag(fidx, u+1);
      }
      { // reload decoder l1 weights
        const unsigned* sA = (const unsigned*)(p.Wd1ih + (size_t)nt*64*512);
        const unsigned* sB = (const unsigned*)(p.Wd1hh + (size_t)nt*64*512);
        unsigned* dA = (unsigned*)WA; unsigned* dB = (unsigned*)WB;
        for (int i = tid; i < 64*256; i += 256){
          int r = i>>8, c = i&255;
          dA[r*260+c] = sA[r*256+c]; dB[r*260+c] = sB[r*256+c];
        }
      }
      biasp = p.Bs + 6144 + nt*64;
      __syncthreads();
      for (int s = 0; s < 12; ++s){
        if (wv == 0) pollF(F, mh, 257+s, 256+s, s-2, t0);   // heads WAR: fh>=s-2
        __syncthreads();
        lstm_step<16,HC,HC>(p.h0b + hslot(256+s)*HB, 512, WA, 520,
                            p.h1b + hslot(255+s)*HB, WB,
                            biasp, p.h1b + hslot(256+s)*HB, creg, g, mh, nt, wv, lane);
        setflag(fidx, 257+s);
      }
    }
  } else if (w < 130){
    // ---- heads wg (one per mh half) ----
    const int mh = w & 1;
    const int b = tid & 63, part = tid >> 6;
    const int gb = mh*64 + b;
    { // cls + reg from h1(255)
      if (wv == 0) pollF(F, mh, 0, 256, 0, t0);
      __syncthreads();
      const u64* hp = (const u64*)(p.h1b + hslot(255)*HB + gb*512 + part*128);
      float a[5] = {0.f,0.f,0.f,0.f,0.f};
      for (int c = 0; c < 32; ++c){
        u64 v = DEEP ? hp[c] : ldc64(hp + c);
        #pragma unroll
        for (int e = 0; e < 4; ++e){
          float hv = b2f((u16)(v >> (16*e)));
          int k = part*128 + c*4 + e;
          a[0] += hv * p.clsW[k];
          a[1] += hv * p.clsW[512 + k];
          a[2] += hv * p.clsW[1024 + k];
          a[3] += hv * p.clsW[1536 + k];
          a[4] += hv * p.regW[k];
        }
      }
      #pragma unroll
      for (int d = 0; d < 5; ++d) g[b][part*8 + d] = a[d];
      __syncthreads();
      if (tid < 64){
        #pragma unroll
        for (int d = 0; d < 5; ++d){
          float v = g[tid][d] + g[tid][8+d] + g[tid][16+d] + g[tid][24+d];
          if (d < 4) p.out[9216 + (mh*64 + tid)*4 + d] = v + p.clsb[d];
          else       p.out[9728 + mh*64 + tid]         = v + p.regb[0];
        }
      }
      __syncthreads();
      if (tid == 0) __hip_atomic_store(F + 128 + mh, 1u, __ATOMIC_RELAXED, SCOPE_AGENT);
    }
    for (int s = 0; s < 12; ++s){
      if (wv == 0) pollF(F, mh, 0, 257 + s, 0, t0);
      __syncthreads();
      const u64* hp = (const u64*)(p.h1b + hslot(256+s)*HB + gb*512 + part*128);
      float a[6] = {0.f,0.f,0.f,0.f,0.f,0.f};
      for (int c = 0; c < 32; ++c){
        u64 v = DEEP ? hp[c] : ldc64(hp + c);
        #pragma unroll
        for (int e = 0; e < 4; ++e){
          float hv = b2f((u16)(v >> (16*e)));
          int k = part*128 + c*4 + e;
          #pragma unroll
          for (int d = 0; d < 6; ++d) a[d] += hv * p.fcW[d*512 + k];
        }
      }
      #pragma unroll
      for (int d = 0; d < 6; ++d) g[b][part*8 + d] = a[d];
      __syncthreads();
      if (tid < 64){
        #pragma unroll
        for (int d = 0; d < 6; ++d){
          float v = g[tid][d] + g[tid][8+d] + g[tid][16+d] + g[tid][24+d];
          p.out[(mh*64 + tid)*72 + s*6 + d] = v + p.fcb[d];
        }
      }
      __syncthreads();
      if (tid == 0)
        __hip_atomic_store(F + 128 + mh, (unsigned)(s+2), __ATOMIC_RELAXED, SCOPE_AGENT);
    }
  }
}

// ---------------- launcher ----------------

extern "C" void kernel_launch(void* const* d_in, const int* in_sizes, int n_in,
                              void* d_out, int out_size, void* d_ws, size_t ws_size,
                              hipStream_t stream){
  const float* x     = (const float*)d_in[0];
  const float* eWih0 = (const float*)d_in[1];
  const float* eWhh0 = (const float*)d_in[2];
  const float* ebih0 = (const float*)d_in[3];
  const float* ebhh0 = (const float*)d_in[4];
  const float* eWih1 = (const float*)d_in[5];
  const float* eWhh1 = (const float*)d_in[6];
  const float* ebih1 = (const float*)d_in[7];
  const float* ebhh1 = (const float*)d_in[8];
  const float* dWih0 = (const float*)d_in[9];
  const float* dWhh0 = (const float*)d_in[10];
  const float* dbih0 = (const float*)d_in[11];
  const float* dbhh0 = (const float*)d_in[12];
  const float* dWih1 = (const float*)d_in[13];
  const float* dWhh1 = (const float*)d_in[14];
  const float* dbih1 = (const float*)d_in[15];
  const float* dbhh1 = (const float*)d_in[16];
  const float* fcW   = (const float*)d_in[17];
  const float* fcb   = (const float*)d_in[18];
  const float* clsW  = (const float*)d_in[19];
  const float* clsb  = (const float*)d_in[20];
  const float* regW  = (const float*)d_in[21];
  const float* regb  = (const float*)d_in[22];
  float* out = (float*)d_out;

  uintptr_t base = (uintptr_t)d_ws;
  auto carve = [&](size_t n)->void*{
    void* p = (void*)base; base += (n + 255) & ~(size_t)255; return p;
  };
  u16* Wx0b  = (u16*)carve(2048*32*2);
  u16* We0hh = (u16*)carve(2048*512*2);
  u16* We1ih = (u16*)carve(2048*512*2);
  u16* We1hh = (u16*)carve(2048*512*2);
  u16* Wd0ih = (u16*)carve(2048*512*2);
  u16* Wd0hh = (u16*)carve(2048*512*2);
  u16* Wd1ih = (u16*)carve(2048*512*2);
  u16* Wd1hh = (u16*)carve(2048*512*2);
  float* Bs  = (float*)carve(4*2048*4);
  u16* Xb    = (u16*)carve(256*128*32*2);

  // decide ring depth from remaining workspace (deep = one slot per timestep)
  const size_t slotB   = (size_t)HB*2;                 // 131072 B per slot
  const size_t usedFix = (size_t)(base - (uintptr_t)d_ws);
  const size_t needDeep = usedFix + 2*( (size_t)NSLOT*slotB + 256 ) + 4096;
  const bool deep = (ws_size >= needDeep);
  const size_t nslot = deep ? (size_t)NSLOT : 4;

  u16* h0b   = (u16*)carve(nslot*slotB);
  u16* h1b   = (u16*)carve(nslot*slotB);
  unsigned* F = (unsigned*)carve(192*4);

  if (deep){
    // zero only slot 0 of each ring (h(-1) = 0) + flags
    (void)hipMemsetAsync(h0b, 0, slotB, stream);
    (void)hipMemsetAsync(h1b, 0, slotB, stream);
    (void)hipMemsetAsync(F,   0, 768,   stream);
  } else {
    // R8 layout: rings + flags contiguous
    (void)hipMemsetAsync(h0b, 0, 2*nslot*slotB + 768, stream);
  }

  reorder_w_k<<<4096,256,0,stream>>>(eWhh0, We0hh);
  reorder_w_k<<<4096,256,0,stream>>>(eWih1, We1ih);
  reorder_w_k<<<4096,256,0,stream>>>(eWhh1, We1hh);
  reorder_w_k<<<4096,256,0,stream>>>(dWih0, Wd0ih);
  reorder_w_k<<<4096,256,0,stream>>>(dWhh0, Wd0hh);
  reorder_w_k<<<4096,256,0,stream>>>(dWih1, Wd1ih);
  reorder_w_k<<<4096,256,0,stream>>>(dWhh1, Wd1hh);
  prep_wx0_k<<<256,256,0,stream>>>(eWih0, Wx0b);
  prep_bias_k<<<8,256,0,stream>>>(ebih0, ebhh0, Bs);
  prep_bias_k<<<8,256,0,stream>>>(ebih1, ebhh1, Bs + 2048);
  prep_bias_k<<<8,256,0,stream>>>(dbih0, dbhh0, Bs + 4096);
  prep_bias_k<<<8,256,0,stream>>>(dbih1, dbhh1, Bs + 6144);
  prep_x_k<<<4096,256,0,stream>>>(x, Xb);

  PK p;
  p.Xb = Xb; p.Wx0 = Wx0b; p.W0hh = We0hh; p.W1ih = We1ih; p.W1hh = We1hh;
  p.Wd0ih = Wd0ih; p.Wd0hh = Wd0hh; p.Wd1ih = Wd1ih; p.Wd1hh = Wd1hh;
  p.Bs = Bs; p.h0b = h0b; p.h1b = h1b; p.F = F;
  p.fcW = fcW; p.fcb = fcb; p.clsW = clsW; p.clsb = clsb;
  p.regW = regW; p.regb = regb; p.out = out;

  const int dynLds = 2*64*520*2;   // 133,120 B (two 64x520 u16 weight slices)
  const void* kfun = deep ? (const void*)persist_k<true> : (const void*)persist_k<false>;
  (void)hipFuncSetAttribute(kfun, hipFuncAttributeMaxDynamicSharedMemorySize, dynLds);

  void* args[] = { &p };
  hipError_t e = hipLaunchCooperativeKernel(kfun, dim3(130), dim3(256),
                                            args, dynLds, stream);
  if (e != hipSuccess){
    // fallback: plain launch (130 wgs at 1 wg/CU are trivially co-resident;
    // poll deadline guards the pathological case)
    if (deep) persist_k<true><<<dim3(130), dim3(256), dynLds, stream>>>(p);
    else      persist_k<false><<<dim3(130), dim3(256), dynLds, stream>>>(p);
  }
  (void)in_sizes; (void)n_in; (void)out_size; (void)ws_size;
}